// Round 1
// baseline (25.253 us; speedup 1.0000x reference)
//
#include <hip/hip_runtime.h>

// Problem constants (from reference): B=8, TIMES=288, N=207, D=64, FEA_IN=295
#define B_     8
#define TIMES_ 288
#define NN_    207
#define D_     64

// One block per (b,t). 256 threads.
// Phase 1 (tid<64):  h[j]   = relu(W1[dow,j] + W1[7+tod,j] + b1[j])
// Phase 2 (tid<64):  row[e] = b2[e] + sum_j h[j] * W2[j,e]
// Phase 3 (all 256): broadcast row to out[b,t,0..N-1,:] as float4 (coalesced).
__global__ __launch_bounds__(256) void TemEmbedding_45672682225716_kernel(
    const int*   __restrict__ TE,   // (B, TIMES, N, 2) int32
    const float* __restrict__ W1,   // (295, 64)
    const float* __restrict__ b1,   // (64,)
    const float* __restrict__ W2,   // (64, 64)
    const float* __restrict__ b2,   // (64,)
    float*       __restrict__ out)  // (B, TIMES, N, 64)
{
    __shared__ float h[D_];
    __shared__ float row[D_];

    const int bt  = blockIdx.x;          // 0 .. B*TIMES-1
    const int tid = threadIdx.x;

    // te = TE[b, t, 0, :]
    const long long te_off = (long long)bt * (NN_ * 2);
    int dow = TE[te_off + 0] % 7;
    if (dow < 0) dow += 7;
    int tod = TE[te_off + 1] % 288;
    if (tod < 0) tod += 288;

    if (tid < D_) {
        float v = W1[dow * D_ + tid] + W1[(7 + tod) * D_ + tid] + b1[tid];
        h[tid] = v > 0.0f ? v : 0.0f;
    }
    __syncthreads();

    if (tid < D_) {
        float acc = b2[tid];
        #pragma unroll
        for (int j = 0; j < D_; ++j) {
            acc = fmaf(h[j], W2[j * D_ + tid], acc);  // coalesced W2 row reads, L2-hit
        }
        row[tid] = acc;
    }
    __syncthreads();

    // Broadcast write: NN_*D_ floats = NN_*16 float4 per block, fully coalesced.
    float4*       out4 = (float4*)(out + (long long)bt * (NN_ * D_));
    const float4* row4 = (const float4*)row;
    const int total4 = NN_ * (D_ / 4);   // 3312
    for (int i = tid; i < total4; i += 256) {
        out4[i] = row4[i & 15];
    }
}

extern "C" void kernel_launch(void* const* d_in, const int* in_sizes, int n_in,
                              void* d_out, int out_size, void* d_ws, size_t ws_size,
                              hipStream_t stream) {
    const int*   TE = (const int*)  d_in[0];
    const float* W1 = (const float*)d_in[1];
    const float* b1 = (const float*)d_in[2];
    const float* W2 = (const float*)d_in[3];
    const float* b2 = (const float*)d_in[4];
    // d_in[5] is T=288 (scalar) — baked into the modulo above.
    float* out = (float*)d_out;

    dim3 grid(B_ * TIMES_);
    dim3 block(256);
    TemEmbedding_45672682225716_kernel<<<grid, block, 0, stream>>>(TE, W1, b1, W2, b2, out);
}